// Round 1
// baseline (3045.352 us; speedup 1.0000x reference)
//
#include <hip/hip_runtime.h>

#define DIM 64
#define NCLS 249

// ---------------- zero ----------------
__global__ void zero_f32(float4* __restrict__ p, int n4) {
    int i = blockIdx.x * blockDim.x + threadIdx.x;
    int stride = gridDim.x * blockDim.x;
    float4 z = make_float4(0.f, 0.f, 0.f, 0.f);
    for (; i < n4; i += stride) p[i] = z;
}

// ---------------- scatter-add (push aggregation) ----------------
// 16 threads per edge, each handles 4 contiguous dims (float4 gather, 4 atomics)
__global__ void scatter_add(const float* __restrict__ feat,
                            const int* __restrict__ ei, int E,
                            float* __restrict__ agg) {
    long gid = (long)blockIdx.x * blockDim.x + threadIdx.x;
    long total = (long)E * 16;
    if (gid >= total) return;
    int e = (int)(gid >> 4);
    int q = (int)(gid & 15);
    int src = ei[e];
    int dst = ei[E + e];
    const float4 v = *(const float4*)(feat + (long)src * DIM + q * 4);
    float* a = agg + (long)dst * DIM + q * 4;
    atomicAdd(a + 0, v.x);
    atomicAdd(a + 1, v.y);
    atomicAdd(a + 2, v.z);
    atomicAdd(a + 3, v.w);
}

// ---------------- layer 1: h = relu(agg @ Wl^T + b + x @ Wr^T) ----------------
// block = 256 threads = 4 nodes x 64 output dims; W matrices staged in LDS
__global__ __launch_bounds__(256) void layer1_kernel(
    const float* __restrict__ x, const float* __restrict__ agg,
    const float* __restrict__ W_l, const float* __restrict__ b_l,
    const float* __restrict__ W_r, float* __restrict__ h, int n_nodes) {
    __shared__ float Wl[64][65];   // +1 pad: bank = (o+k)%32, 2-way (free)
    __shared__ float Wr[64][65];
    __shared__ float arow[4][64];
    __shared__ float xrow[4][64];
    int tid = threadIdx.x;
    for (int i = tid; i < 4096; i += 256) {
        Wl[i >> 6][i & 63] = W_l[i];
        Wr[i >> 6][i & 63] = W_r[i];
    }
    int o = tid & 63;
    int nl = tid >> 6;                 // 0..3, wave-uniform
    int node = blockIdx.x * 4 + nl;
    bool ok = node < n_nodes;
    arow[nl][o] = ok ? agg[(long)node * DIM + o] : 0.f;
    xrow[nl][o] = ok ? x[(long)node * DIM + o] : 0.f;
    __syncthreads();
    float acc = b_l[o];
#pragma unroll
    for (int k = 0; k < 64; ++k)
        acc += arow[nl][k] * Wl[o][k] + xrow[nl][k] * Wr[o][k];
    if (ok) h[(long)node * DIM + o] = fmaxf(acc, 0.f);
}

// ---------------- transpose 249x64 -> 64x249 ----------------
__global__ void transpose_w(const float* __restrict__ W, float* __restrict__ WT) {
    int i = blockIdx.x * blockDim.x + threadIdx.x;
    if (i >= NCLS * 64) return;
    int c = i / 64, k = i % 64;
    WT[k * NCLS + c] = W[i];
}

// ---------------- layer 2: out = agg @ Wl^T + b + h @ Wr^T ----------------
// block = 256 threads; 8 nodes per block; thread c = class; W reads coalesced via WT
__global__ __launch_bounds__(256) void layer2_kernel(
    const float* __restrict__ h, const float* __restrict__ agg,
    const float* __restrict__ WlT, const float* __restrict__ WrT,
    const float* __restrict__ b, float* __restrict__ out, int n_nodes) {
    const int NT = 8;
    __shared__ float arow[NT][64];
    __shared__ float hrow[NT][64];
    int tid = threadIdx.x;
    int node0 = blockIdx.x * NT;
    for (int i = tid; i < NT * 64; i += 256) {
        int n = i >> 6, k = i & 63;
        long idx = (long)(node0 + n) * DIM + k;
        bool ok = (node0 + n) < n_nodes;
        arow[n][k] = ok ? agg[idx] : 0.f;
        hrow[n][k] = ok ? h[idx] : 0.f;
    }
    __syncthreads();
    int c = tid;
    if (c >= NCLS) return;
    float acc[NT];
    float bc = b[c];
#pragma unroll
    for (int n = 0; n < NT; ++n) acc[n] = bc;
    for (int k = 0; k < 64; ++k) {
        float wl = WlT[k * NCLS + c];
        float wr = WrT[k * NCLS + c];
#pragma unroll
        for (int n = 0; n < NT; ++n)
            acc[n] += arow[n][k] * wl + hrow[n][k] * wr;
    }
#pragma unroll
    for (int n = 0; n < NT; ++n) {
        int node = node0 + n;
        if (node < n_nodes) out[(long)node * NCLS + c] = acc[n];
    }
}

extern "C" void kernel_launch(void* const* d_in, const int* in_sizes, int n_in,
                              void* d_out, int out_size, void* d_ws, size_t ws_size,
                              hipStream_t stream) {
    const float* x   = (const float*)d_in[0];
    const int*   ei  = (const int*)d_in[1];
    const float* W1l = (const float*)d_in[2];
    const float* b1  = (const float*)d_in[3];
    const float* W1r = (const float*)d_in[4];
    const float* W2l = (const float*)d_in[5];
    const float* b2  = (const float*)d_in[6];
    const float* W2r = (const float*)d_in[7];
    float* out = (float*)d_out;

    const int N = in_sizes[0] / DIM;     // 100000
    const int E = in_sizes[1] / 2;       // 1600000

    float* agg = (float*)d_ws;
    float* h   = agg + (size_t)N * DIM;
    float* WlT = h + (size_t)N * DIM;
    float* WrT = WlT + (size_t)NCLS * DIM;

    const int nf4 = N * DIM / 4;
    const int scatter_blocks = (int)(((long)E * 16 + 255) / 256);

    // weight transposes (independent of everything else)
    transpose_w<<<(NCLS * DIM + 255) / 256, 256, 0, stream>>>(W2l, WlT);
    transpose_w<<<(NCLS * DIM + 255) / 256, 256, 0, stream>>>(W2r, WrT);

    // layer 1
    zero_f32<<<2048, 256, 0, stream>>>((float4*)agg, nf4);
    scatter_add<<<scatter_blocks, 256, 0, stream>>>(x, ei, E, agg);
    layer1_kernel<<<(N + 3) / 4, 256, 0, stream>>>(x, agg, W1l, b1, W1r, h, N);

    // layer 2
    zero_f32<<<2048, 256, 0, stream>>>((float4*)agg, nf4);
    scatter_add<<<scatter_blocks, 256, 0, stream>>>(h, ei, E, agg);
    layer2_kernel<<<(N + 7) / 8, 256, 0, stream>>>(h, agg, WlT, WrT, b2, out, N);
}

// Round 2
// 620.892 us; speedup vs baseline: 4.9048x; 4.9048x over previous
//
#include <hip/hip_runtime.h>

#define DIM 64
#define NCLS 249
#define SCAN_CHUNK 1024

// ---------------- zero int ----------------
__global__ void zero_i32(int* __restrict__ p, int n) {
    int i = blockIdx.x * blockDim.x + threadIdx.x;
    int stride = gridDim.x * blockDim.x;
    for (; i < n; i += stride) p[i] = 0;
}

// ---------------- CSR build: histogram of dst ----------------
__global__ void hist_kernel(const int* __restrict__ ei, int E, int* __restrict__ cnt) {
    int e = blockIdx.x * blockDim.x + threadIdx.x;
    if (e < E) atomicAdd(&cnt[ei[E + e]], 1);
}

// ---------------- scan pass 1: per-block (1024-elem chunk) sums ----------------
__global__ __launch_bounds__(256) void scan_block_sums(const int* __restrict__ cnt, int n,
                                                       int* __restrict__ bsum) {
    __shared__ int sdata[256];
    int b = blockIdx.x, t = threadIdx.x;
    int base = b * SCAN_CHUNK;
    int s = 0;
    for (int i = t; i < SCAN_CHUNK; i += 256) {
        int idx = base + i;
        s += (idx < n) ? cnt[idx] : 0;
    }
    sdata[t] = s;
    __syncthreads();
    for (int off = 128; off > 0; off >>= 1) {
        if (t < off) sdata[t] += sdata[t + off];
        __syncthreads();
    }
    if (t == 0) bsum[b] = sdata[0];
}

// ---------------- scan pass 2: single-block exclusive scan of block sums ----------------
__global__ __launch_bounds__(1024) void scan_bsum(int* __restrict__ bsum, int nb) {
    __shared__ int tmp[1024];
    int t = threadIdx.x;
    int v = (t < nb) ? bsum[t] : 0;
    tmp[t] = v;
    __syncthreads();
    for (int off = 1; off < 1024; off <<= 1) {
        int u = (t >= off) ? tmp[t - off] : 0;
        __syncthreads();
        tmp[t] += u;
        __syncthreads();
    }
    if (t < nb) bsum[t] = tmp[t] - v;   // exclusive
}

// ---------------- scan pass 3: per-block exclusive scan -> row_ptr & cursor ----------------
__global__ __launch_bounds__(256) void scan_final(const int* __restrict__ cnt, int n,
                                                  const int* __restrict__ bsum,
                                                  int* __restrict__ row_ptr,
                                                  int* __restrict__ cursor, int E) {
    __shared__ int tsum[256];
    int b = blockIdx.x, t = threadIdx.x;
    int base = b * SCAN_CHUNK + t * 4;
    int v[4];
    int s = 0;
#pragma unroll
    for (int i = 0; i < 4; ++i) {
        int id = base + i;
        v[i] = (id < n) ? cnt[id] : 0;
        s += v[i];
    }
    tsum[t] = s;
    __syncthreads();
    for (int off = 1; off < 256; off <<= 1) {
        int u = (t >= off) ? tsum[t - off] : 0;
        __syncthreads();
        tsum[t] += u;
        __syncthreads();
    }
    int run = tsum[t] - s + bsum[b];
#pragma unroll
    for (int i = 0; i < 4; ++i) {
        int id = base + i;
        if (id < n) { row_ptr[id] = run; cursor[id] = run; }
        run += v[i];
    }
    if (b == 0 && t == 0) row_ptr[n] = E;
}

// ---------------- CSR fill ----------------
__global__ void fill_kernel(const int* __restrict__ ei, int E,
                            int* __restrict__ cursor, int* __restrict__ nbr) {
    int e = blockIdx.x * blockDim.x + threadIdx.x;
    if (e >= E) return;
    int src = ei[e];
    int dst = ei[E + e];
    int pos = atomicAdd(&cursor[dst], 1);
    nbr[pos] = src;
}

// ---------------- pull aggregation: agg[n] = sum_{j in N(n)} feat[j] ----------------
// 16 lanes per node, one float4 per lane -> 256B contiguous gather per neighbor
__global__ __launch_bounds__(256) void pull_kernel(const float* __restrict__ feat,
                                                   const int* __restrict__ row_ptr,
                                                   const int* __restrict__ nbr,
                                                   float* __restrict__ agg, int n) {
    int tid = blockIdx.x * 256 + threadIdx.x;
    int node = tid >> 4;
    int q = tid & 15;
    if (node >= n) return;
    int beg = row_ptr[node], end = row_ptr[node + 1];
    float4 acc = make_float4(0.f, 0.f, 0.f, 0.f);
    for (int j = beg; j < end; ++j) {
        int s = nbr[j];
        const float4 v = *(const float4*)(feat + (long)s * DIM + q * 4);
        acc.x += v.x; acc.y += v.y; acc.z += v.z; acc.w += v.w;
    }
    *(float4*)(agg + (long)node * DIM + q * 4) = acc;
}

// ---------------- layer 1: h = relu(agg @ Wl^T + b + x @ Wr^T) ----------------
__global__ __launch_bounds__(256) void layer1_kernel(
    const float* __restrict__ x, const float* __restrict__ agg,
    const float* __restrict__ W_l, const float* __restrict__ b_l,
    const float* __restrict__ W_r, float* __restrict__ h, int n_nodes) {
    __shared__ float Wl[64][65];
    __shared__ float Wr[64][65];
    __shared__ float arow[4][64];
    __shared__ float xrow[4][64];
    int tid = threadIdx.x;
    for (int i = tid; i < 4096; i += 256) {
        Wl[i >> 6][i & 63] = W_l[i];
        Wr[i >> 6][i & 63] = W_r[i];
    }
    int o = tid & 63;
    int nl = tid >> 6;
    int node = blockIdx.x * 4 + nl;
    bool ok = node < n_nodes;
    arow[nl][o] = ok ? agg[(long)node * DIM + o] : 0.f;
    xrow[nl][o] = ok ? x[(long)node * DIM + o] : 0.f;
    __syncthreads();
    float acc = b_l[o];
#pragma unroll
    for (int k = 0; k < 64; ++k)
        acc += arow[nl][k] * Wl[o][k] + xrow[nl][k] * Wr[o][k];
    if (ok) h[(long)node * DIM + o] = fmaxf(acc, 0.f);
}

// ---------------- transpose 249x64 -> 64x249 ----------------
__global__ void transpose_w(const float* __restrict__ W, float* __restrict__ WT) {
    int i = blockIdx.x * blockDim.x + threadIdx.x;
    if (i >= NCLS * 64) return;
    int c = i / 64, k = i % 64;
    WT[k * NCLS + c] = W[i];
}

// ---------------- layer 2: out = agg @ Wl^T + b + h @ Wr^T ----------------
__global__ __launch_bounds__(256) void layer2_kernel(
    const float* __restrict__ h, const float* __restrict__ agg,
    const float* __restrict__ WlT, const float* __restrict__ WrT,
    const float* __restrict__ b, float* __restrict__ out, int n_nodes) {
    const int NT = 8;
    __shared__ float arow[NT][64];
    __shared__ float hrow[NT][64];
    int tid = threadIdx.x;
    int node0 = blockIdx.x * NT;
    for (int i = tid; i < NT * 64; i += 256) {
        int n = i >> 6, k = i & 63;
        long idx = (long)(node0 + n) * DIM + k;
        bool ok = (node0 + n) < n_nodes;
        arow[n][k] = ok ? agg[idx] : 0.f;
        hrow[n][k] = ok ? h[idx] : 0.f;
    }
    __syncthreads();
    int c = tid;
    if (c >= NCLS) return;
    float acc[NT];
    float bc = b[c];
#pragma unroll
    for (int n = 0; n < NT; ++n) acc[n] = bc;
    for (int k = 0; k < 64; ++k) {
        float wl = WlT[k * NCLS + c];
        float wr = WrT[k * NCLS + c];
#pragma unroll
        for (int n = 0; n < NT; ++n)
            acc[n] += arow[n][k] * wl + hrow[n][k] * wr;
    }
#pragma unroll
    for (int n = 0; n < NT; ++n) {
        int node = node0 + n;
        if (node < n_nodes) out[(long)node * NCLS + c] = acc[n];
    }
}

extern "C" void kernel_launch(void* const* d_in, const int* in_sizes, int n_in,
                              void* d_out, int out_size, void* d_ws, size_t ws_size,
                              hipStream_t stream) {
    const float* x   = (const float*)d_in[0];
    const int*   ei  = (const int*)d_in[1];
    const float* W1l = (const float*)d_in[2];
    const float* b1  = (const float*)d_in[3];
    const float* W1r = (const float*)d_in[4];
    const float* W2l = (const float*)d_in[5];
    const float* b2  = (const float*)d_in[6];
    const float* W2r = (const float*)d_in[7];
    float* out = (float*)d_out;

    const int N = in_sizes[0] / DIM;     // 100000
    const int E = in_sizes[1] / 2;       // 1600000
    const int NB = (N + SCAN_CHUNK - 1) / SCAN_CHUNK;   // 98 scan blocks

    // workspace layout
    float* agg     = (float*)d_ws;                       // N*64
    float* h       = agg + (size_t)N * DIM;              // N*64
    float* WlT     = h + (size_t)N * DIM;                // NCLS*64
    float* WrT     = WlT + (size_t)NCLS * DIM;           // NCLS*64
    int*   cnt     = (int*)(WrT + (size_t)NCLS * DIM);   // N
    int*   row_ptr = cnt + N;                            // N+1
    int*   cursor  = row_ptr + N + 1;                    // N
    int*   bsum    = cursor + N;                         // 1024 (padded)
    int*   nbr     = bsum + 1024;                        // E

    // ---- CSR build ----
    zero_i32<<<512, 256, 0, stream>>>(cnt, N);
    hist_kernel<<<(E + 255) / 256, 256, 0, stream>>>(ei, E, cnt);
    scan_block_sums<<<NB, 256, 0, stream>>>(cnt, N, bsum);
    scan_bsum<<<1, 1024, 0, stream>>>(bsum, NB);
    scan_final<<<NB, 256, 0, stream>>>(cnt, N, bsum, row_ptr, cursor, E);
    fill_kernel<<<(E + 255) / 256, 256, 0, stream>>>(ei, E, cursor, nbr);

    // ---- weight transposes ----
    transpose_w<<<(NCLS * DIM + 255) / 256, 256, 0, stream>>>(W2l, WlT);
    transpose_w<<<(NCLS * DIM + 255) / 256, 256, 0, stream>>>(W2r, WrT);

    // ---- layer 1 ----
    pull_kernel<<<(N * 16 + 255) / 256, 256, 0, stream>>>(x, row_ptr, nbr, agg, N);
    layer1_kernel<<<(N + 3) / 4, 256, 0, stream>>>(x, agg, W1l, b1, W1r, h, N);

    // ---- layer 2 ----
    pull_kernel<<<(N * 16 + 255) / 256, 256, 0, stream>>>(h, row_ptr, nbr, agg, N);
    layer2_kernel<<<(N + 7) / 8, 256, 0, stream>>>(h, agg, WlT, WrT, b2, out, N);
}

// Round 3
// 355.454 us; speedup vs baseline: 8.5675x; 1.7468x over previous
//
#include <hip/hip_runtime.h>

#define DIM 64
#define NCLS 249
#define SCAN_CHUNK 1024

typedef unsigned int u32;
typedef unsigned short u16;
using bf16x8 = __attribute__((ext_vector_type(8))) short;
using f32x4  = __attribute__((ext_vector_type(4))) float;

__device__ __forceinline__ u16 f2bf(float f) {
    u32 u = __builtin_bit_cast(u32, f);
    u += 0x7FFFu + ((u >> 16) & 1u);   // round-to-nearest-even
    return (u16)(u >> 16);
}
__device__ __forceinline__ float bf_lo(u32 u) { return __builtin_bit_cast(float, u << 16); }
__device__ __forceinline__ float bf_hi(u32 u) { return __builtin_bit_cast(float, u & 0xFFFF0000u); }

// ---------------- zero int ----------------
__global__ void zero_i32(int* __restrict__ p, int n) {
    int i = blockIdx.x * blockDim.x + threadIdx.x;
    int stride = gridDim.x * blockDim.x;
    for (; i < n; i += stride) p[i] = 0;
}

// ---------------- CSR build ----------------
__global__ void hist_kernel(const int* __restrict__ ei, int E, int* __restrict__ cnt) {
    int e = blockIdx.x * blockDim.x + threadIdx.x;
    if (e < E) atomicAdd(&cnt[ei[E + e]], 1);
}

__global__ __launch_bounds__(256) void scan_block_sums(const int* __restrict__ cnt, int n,
                                                       int* __restrict__ bsum) {
    __shared__ int sdata[256];
    int b = blockIdx.x, t = threadIdx.x;
    int base = b * SCAN_CHUNK;
    int s = 0;
    for (int i = t; i < SCAN_CHUNK; i += 256) {
        int idx = base + i;
        s += (idx < n) ? cnt[idx] : 0;
    }
    sdata[t] = s;
    __syncthreads();
    for (int off = 128; off > 0; off >>= 1) {
        if (t < off) sdata[t] += sdata[t + off];
        __syncthreads();
    }
    if (t == 0) bsum[b] = sdata[0];
}

__global__ __launch_bounds__(1024) void scan_bsum(int* __restrict__ bsum, int nb) {
    __shared__ int tmp[1024];
    int t = threadIdx.x;
    int v = (t < nb) ? bsum[t] : 0;
    tmp[t] = v;
    __syncthreads();
    for (int off = 1; off < 1024; off <<= 1) {
        int u = (t >= off) ? tmp[t - off] : 0;
        __syncthreads();
        tmp[t] += u;
        __syncthreads();
    }
    if (t < nb) bsum[t] = tmp[t] - v;
}

__global__ __launch_bounds__(256) void scan_final(const int* __restrict__ cnt, int n,
                                                  const int* __restrict__ bsum,
                                                  int* __restrict__ row_ptr,
                                                  int* __restrict__ cursor, int E) {
    __shared__ int tsum[256];
    int b = blockIdx.x, t = threadIdx.x;
    int base = b * SCAN_CHUNK + t * 4;
    int v[4];
    int s = 0;
#pragma unroll
    for (int i = 0; i < 4; ++i) {
        int id = base + i;
        v[i] = (id < n) ? cnt[id] : 0;
        s += v[i];
    }
    tsum[t] = s;
    __syncthreads();
    for (int off = 1; off < 256; off <<= 1) {
        int u = (t >= off) ? tsum[t - off] : 0;
        __syncthreads();
        tsum[t] += u;
        __syncthreads();
    }
    int run = tsum[t] - s + bsum[b];
#pragma unroll
    for (int i = 0; i < 4; ++i) {
        int id = base + i;
        if (id < n) { row_ptr[id] = run; cursor[id] = run; }
        run += v[i];
    }
    if (b == 0 && t == 0) row_ptr[n] = E;
}

__global__ void fill_kernel(const int* __restrict__ ei, int E,
                            int* __restrict__ cursor, int* __restrict__ nbr) {
    int e = blockIdx.x * blockDim.x + threadIdx.x;
    if (e >= E) return;
    int src = ei[e];
    int dst = ei[E + e];
    int pos = atomicAdd(&cursor[dst], 1);
    nbr[pos] = src;
}

// ---------------- convert x (f32) -> bf16 into A1 cols 64..127 ----------------
__global__ void convert_x(const float* __restrict__ x, u16* __restrict__ A1, int total) {
    int i = blockIdx.x * 256 + threadIdx.x;   // group of 8 elements
    if (i >= total) return;
    int node = i >> 3, seg = i & 7;
    const float4 v0 = *(const float4*)(x + (size_t)i * 8);
    const float4 v1 = *(const float4*)(x + (size_t)i * 8 + 4);
    uint4 o;
    o.x = (u32)f2bf(v0.x) | ((u32)f2bf(v0.y) << 16);
    o.y = (u32)f2bf(v0.z) | ((u32)f2bf(v0.w) << 16);
    o.z = (u32)f2bf(v1.x) | ((u32)f2bf(v1.y) << 16);
    o.w = (u32)f2bf(v1.z) | ((u32)f2bf(v1.w) << 16);
    *(uint4*)(A1 + (size_t)node * 128 + 64 + seg * 8) = o;
}

// ---------------- prep weights: B[r][128] = bf16([Wl[r]|Wr[r]]), zero-padded rows ----------------
__global__ void prep_B(const float* __restrict__ Wl, const float* __restrict__ Wr,
                       u16* __restrict__ B, int nrows_src, int nrows_dst) {
    int i = blockIdx.x * 256 + threadIdx.x;
    if (i >= nrows_dst * 128) return;
    int r = i >> 7, k = i & 127;
    float v = 0.f;
    if (r < nrows_src) v = (k < 64) ? Wl[r * 64 + k] : Wr[r * 64 + k - 64];
    B[i] = f2bf(v);
}

// ---------------- pull aggregation on bf16 panels ----------------
// Asrc: feature at cols 64..127 of [*,128] bf16 panel; Adst: cols 0..63 of [*,128]
// 8 lanes per node, each lane one 16B granule (8 bf16); accumulate f32.
__global__ __launch_bounds__(256) void pull_bf16(const u16* __restrict__ Asrc,
                                                 const int* __restrict__ row_ptr,
                                                 const int* __restrict__ nbr,
                                                 u16* __restrict__ Adst, int n) {
    int tid = blockIdx.x * 256 + threadIdx.x;
    int node = tid >> 3;
    int q = tid & 7;
    if (node >= n) return;
    int beg = row_ptr[node], end = row_ptr[node + 1];
    float a0 = 0.f, a1 = 0.f, a2 = 0.f, a3 = 0.f, a4 = 0.f, a5 = 0.f, a6 = 0.f, a7 = 0.f;
    for (int j = beg; j < end; ++j) {
        int s = nbr[j];
        uint4 v = *(const uint4*)(Asrc + (size_t)s * 128 + 64 + q * 8);
        a0 += bf_lo(v.x); a1 += bf_hi(v.x);
        a2 += bf_lo(v.y); a3 += bf_hi(v.y);
        a4 += bf_lo(v.z); a5 += bf_hi(v.z);
        a6 += bf_lo(v.w); a7 += bf_hi(v.w);
    }
    uint4 o;
    o.x = (u32)f2bf(a0) | ((u32)f2bf(a1) << 16);
    o.y = (u32)f2bf(a2) | ((u32)f2bf(a3) << 16);
    o.z = (u32)f2bf(a4) | ((u32)f2bf(a5) << 16);
    o.w = (u32)f2bf(a6) | ((u32)f2bf(a7) << 16);
    *(uint4*)(Adst + (size_t)node * 128 + q * 8) = o;
}

// ---------------- MFMA GEMM: [64 nodes] x [NT*16 cols], K=128 ----------------
// A: [npad][128] bf16 panel. B: [NT*16][128] bf16 ([Wl|Wr] rows).
// 4 waves, wave w owns rows w*16..w*16+15, all cols. 16B-granule XOR swizzle in LDS.
template<int NT, bool RELU, bool OUT_BF16>
__global__ __launch_bounds__(256) void gemm_kernel(
    const u16* __restrict__ A, const u16* __restrict__ B,
    const float* __restrict__ bias,
    float* __restrict__ outf, u16* __restrict__ outb,
    int n_nodes, int n_cols)
{
    constexpr int KC = (NT == 16) ? 2 : 1;   // K chunks for B staging
    constexpr int KW = 128 / KC;             // k-width per chunk (bf16 elems)
    constexpr int RG = KW / 8;               // 16B granules per B row
    constexpr int NR = NT * 16;              // B rows
    __shared__ uint4 A_lds[64 * 16];         // 16 KB
    __shared__ uint4 B_lds[2048];            // 32 KB

    const int t = threadIdx.x;
    const int node0 = blockIdx.x * 64;

    // stage A tile (coalesced global, swizzled LDS write)
#pragma unroll
    for (int i = 0; i < 4; ++i) {
        int gl = t + 256 * i;                // linear granule 0..1023
        int r = gl >> 4, g = gl & 15;
        uint4 v = make_uint4(0u, 0u, 0u, 0u);
        int node = node0 + r;
        if (node < n_nodes) v = *(const uint4*)(A + (size_t)node * 128 + g * 8);
        A_lds[r * 16 + (g ^ (r & 7))] = v;
    }

    const int w  = t >> 6;
    const int l  = t & 63;
    const int lm = l & 15;
    const int lg = l >> 4;
    const int arow = w * 16 + lm;
    const int asw  = arow & 7;

    f32x4 acc[NT];
#pragma unroll
    for (int n = 0; n < NT; ++n) acc[n] = f32x4{0.f, 0.f, 0.f, 0.f};

#pragma unroll
    for (int kc = 0; kc < KC; ++kc) {
        __syncthreads();   // protect B_lds reuse (and A staging on first pass)
#pragma unroll
        for (int i = 0; i < (NR * RG) / 256; ++i) {
            int gl = t + 256 * i;
            int r = gl / RG, g = gl % RG;
            uint4 v = *(const uint4*)(B + (size_t)r * 128 + kc * KW + g * 8);
            B_lds[r * RG + (g ^ (r & 7))] = v;
        }
        __syncthreads();
#pragma unroll
        for (int ks = 0; ks < KW / 32; ++ks) {
            int ag = lg + (kc * (KW / 32) + ks) * 4;
            bf16x8 af = __builtin_bit_cast(bf16x8, A_lds[arow * 16 + (ag ^ asw)]);
#pragma unroll
            for (int n = 0; n < NT; ++n) {
                int brow = n * 16 + lm;
                int bg = lg + ks * 4;
                bf16x8 bf = __builtin_bit_cast(bf16x8, B_lds[brow * RG + (bg ^ (brow & 7))]);
                acc[n] = __builtin_amdgcn_mfma_f32_16x16x32_bf16(af, bf, acc[n], 0, 0, 0);
            }
        }
    }

    // epilogue: D col = lane&15 (+tile*16), row = (lane>>4)*4+reg (+wave*16)
    const int rbase = w * 16 + lg * 4;
#pragma unroll
    for (int n = 0; n < NT; ++n) {
        int c = n * 16 + lm;
        float bv = (c < n_cols) ? bias[c] : 0.f;
#pragma unroll
        for (int r = 0; r < 4; ++r) {
            int node = node0 + rbase + r;
            if (node < n_nodes && c < n_cols) {
                float v = acc[n][r] + bv;
                if (RELU) v = fmaxf(v, 0.f);
                if (OUT_BF16) outb[(size_t)node * 128 + 64 + c] = f2bf(v);
                else outf[(size_t)node * (size_t)n_cols + c] = v;
            }
        }
    }
}

extern "C" void kernel_launch(void* const* d_in, const int* in_sizes, int n_in,
                              void* d_out, int out_size, void* d_ws, size_t ws_size,
                              hipStream_t stream) {
    const float* x   = (const float*)d_in[0];
    const int*   ei  = (const int*)d_in[1];
    const float* W1l = (const float*)d_in[2];
    const float* b1  = (const float*)d_in[3];
    const float* W1r = (const float*)d_in[4];
    const float* W2l = (const float*)d_in[5];
    const float* b2  = (const float*)d_in[6];
    const float* W2r = (const float*)d_in[7];
    float* out = (float*)d_out;

    const int N = in_sizes[0] / DIM;     // 100000
    const int E = in_sizes[1] / 2;       // 1600000
    const int NPAD = ((N + 63) / 64) * 64;
    const int NB = (N + SCAN_CHUNK - 1) / SCAN_CHUNK;

    // workspace layout (bytes)
    char* wp = (char*)d_ws;
    u16* A1 = (u16*)wp;                 wp += (size_t)NPAD * 128 * 2;   // [agg1 | xb]
    u16* A2 = (u16*)wp;                 wp += (size_t)NPAD * 128 * 2;   // [agg2 | h]
    u16* B1 = (u16*)wp;                 wp += 64 * 128 * 2;
    u16* B2 = (u16*)wp;                 wp += 256 * 128 * 2;
    int* cnt     = (int*)wp;            wp += (size_t)N * 4;
    int* row_ptr = (int*)wp;            wp += (size_t)(N + 1) * 4;
    int* cursor  = (int*)wp;            wp += (size_t)N * 4;
    int* bsum    = (int*)wp;            wp += 1024 * 4;
    int* nbr     = (int*)wp;

    // ---- CSR build ----
    zero_i32<<<512, 256, 0, stream>>>(cnt, N);
    hist_kernel<<<(E + 255) / 256, 256, 0, stream>>>(ei, E, cnt);
    scan_block_sums<<<NB, 256, 0, stream>>>(cnt, N, bsum);
    scan_bsum<<<1, 1024, 0, stream>>>(bsum, NB);
    scan_final<<<NB, 256, 0, stream>>>(cnt, N, bsum, row_ptr, cursor, E);
    fill_kernel<<<(E + 255) / 256, 256, 0, stream>>>(ei, E, cursor, nbr);

    // ---- conversions / weight prep (independent) ----
    convert_x<<<(N * 8 + 255) / 256, 256, 0, stream>>>(x, A1, N * 8);
    prep_B<<<(64 * 128 + 255) / 256, 256, 0, stream>>>(W1l, W1r, B1, 64, 64);
    prep_B<<<(256 * 128 + 255) / 256, 256, 0, stream>>>(W2l, W2r, B2, NCLS, 256);

    const int gemm_blocks = NPAD / 64;

    // ---- layer 1 ----
    pull_bf16<<<(N * 8 + 255) / 256, 256, 0, stream>>>(A1, row_ptr, nbr, A1, N);
    gemm_kernel<4, true, true><<<gemm_blocks, 256, 0, stream>>>(A1, B1, b1, nullptr, A2, N, 64);

    // ---- layer 2 ----
    pull_bf16<<<(N * 8 + 255) / 256, 256, 0, stream>>>(A2, row_ptr, nbr, A2, N);
    gemm_kernel<16, false, false><<<gemm_blocks, 256, 0, stream>>>(A2, B2, b2, out, nullptr, N, NCLS);
}

// Round 4
// 309.778 us; speedup vs baseline: 9.8308x; 1.1474x over previous
//
#include <hip/hip_runtime.h>

#define DIM 64
#define NCLS 249
#define SCAN_CHUNK 1024
#define NXCD 8

typedef unsigned int u32;
typedef unsigned short u16;
using bf16x8 = __attribute__((ext_vector_type(8))) short;
using f32x4  = __attribute__((ext_vector_type(4))) float;

__device__ __forceinline__ u16 f2bf(float f) {
    u32 u = __builtin_bit_cast(u32, f);
    u += 0x7FFFu + ((u >> 16) & 1u);   // round-to-nearest-even
    return (u16)(u >> 16);
}
__device__ __forceinline__ float bf_lo(u32 u) { return __builtin_bit_cast(float, u << 16); }
__device__ __forceinline__ float bf_hi(u32 u) { return __builtin_bit_cast(float, u & 0xFFFF0000u); }

// ---------------- zero int ----------------
__global__ void zero_i32(int* __restrict__ p, int n) {
    int i = blockIdx.x * blockDim.x + threadIdx.x;
    int stride = gridDim.x * blockDim.x;
    for (; i < n; i += stride) p[i] = 0;
}

// ---------------- CSR build: XCD-partitioned histogram ----------------
// block b: edge chunk (b>>3), dst range (b&7). bid%8 -> XCD round-robin, so all
// atomics for a dst range issue from one XCD -> no cross-XCD line ping-pong.
__global__ __launch_bounds__(256) void hist_part(const int* __restrict__ dst, int E,
                                                 int* __restrict__ cnt,
                                                 int npp, int chunk_size) {
    int part = blockIdx.x & (NXCD - 1);
    int chunk = blockIdx.x >> 3;
    int lo = part * npp, hi = lo + npp;
    int base = chunk * chunk_size;
    int end = min(base + chunk_size, E);
    for (int e = base + threadIdx.x; e < end; e += 256) {
        int d = dst[e];
        if (d >= lo && d < hi) atomicAdd(&cnt[d], 1);
    }
}

__global__ __launch_bounds__(256) void scan_block_sums(const int* __restrict__ cnt, int n,
                                                       int* __restrict__ bsum) {
    __shared__ int sdata[256];
    int b = blockIdx.x, t = threadIdx.x;
    int base = b * SCAN_CHUNK;
    int s = 0;
    for (int i = t; i < SCAN_CHUNK; i += 256) {
        int idx = base + i;
        s += (idx < n) ? cnt[idx] : 0;
    }
    sdata[t] = s;
    __syncthreads();
    for (int off = 128; off > 0; off >>= 1) {
        if (t < off) sdata[t] += sdata[t + off];
        __syncthreads();
    }
    if (t == 0) bsum[b] = sdata[0];
}

__global__ __launch_bounds__(1024) void scan_bsum(int* __restrict__ bsum, int nb) {
    __shared__ int tmp[1024];
    int t = threadIdx.x;
    int v = (t < nb) ? bsum[t] : 0;
    tmp[t] = v;
    __syncthreads();
    for (int off = 1; off < 1024; off <<= 1) {
        int u = (t >= off) ? tmp[t - off] : 0;
        __syncthreads();
        tmp[t] += u;
        __syncthreads();
    }
    if (t < nb) bsum[t] = tmp[t] - v;
}

__global__ __launch_bounds__(256) void scan_final(const int* __restrict__ cnt, int n,
                                                  const int* __restrict__ bsum,
                                                  int* __restrict__ row_ptr,
                                                  int* __restrict__ cursor, int E) {
    __shared__ int tsum[256];
    int b = blockIdx.x, t = threadIdx.x;
    int base = b * SCAN_CHUNK + t * 4;
    int v[4];
    int s = 0;
#pragma unroll
    for (int i = 0; i < 4; ++i) {
        int id = base + i;
        v[i] = (id < n) ? cnt[id] : 0;
        s += v[i];
    }
    tsum[t] = s;
    __syncthreads();
    for (int off = 1; off < 256; off <<= 1) {
        int u = (t >= off) ? tsum[t - off] : 0;
        __syncthreads();
        tsum[t] += u;
        __syncthreads();
    }
    int run = tsum[t] - s + bsum[b];
#pragma unroll
    for (int i = 0; i < 4; ++i) {
        int id = base + i;
        if (id < n) { row_ptr[id] = run; cursor[id] = run; }
        run += v[i];
    }
    if (b == 0 && t == 0) row_ptr[n] = E;
}

// ---------------- CSR fill: XCD-partitioned ----------------
// nbr rows for dst range r are a contiguous region written only from XCD r.
__global__ __launch_bounds__(256) void fill_part(const int* __restrict__ ei, int E,
                                                 int* __restrict__ cursor,
                                                 int* __restrict__ nbr,
                                                 int npp, int chunk_size) {
    int part = blockIdx.x & (NXCD - 1);
    int chunk = blockIdx.x >> 3;
    int lo = part * npp, hi = lo + npp;
    int base = chunk * chunk_size;
    int end = min(base + chunk_size, E);
    for (int e = base + threadIdx.x; e < end; e += 256) {
        int d = ei[E + e];
        if (d >= lo && d < hi) {
            int s = ei[e];
            int pos = atomicAdd(&cursor[d], 1);
            nbr[pos] = s;
        }
    }
}

// ---------------- convert x (f32) -> bf16 into A1 cols 64..127 ----------------
__global__ void convert_x(const float* __restrict__ x, u16* __restrict__ A1, int total) {
    int i = blockIdx.x * 256 + threadIdx.x;   // group of 8 elements
    if (i >= total) return;
    int node = i >> 3, seg = i & 7;
    const float4 v0 = *(const float4*)(x + (size_t)i * 8);
    const float4 v1 = *(const float4*)(x + (size_t)i * 8 + 4);
    uint4 o;
    o.x = (u32)f2bf(v0.x) | ((u32)f2bf(v0.y) << 16);
    o.y = (u32)f2bf(v0.z) | ((u32)f2bf(v0.w) << 16);
    o.z = (u32)f2bf(v1.x) | ((u32)f2bf(v1.y) << 16);
    o.w = (u32)f2bf(v1.z) | ((u32)f2bf(v1.w) << 16);
    *(uint4*)(A1 + (size_t)node * 128 + 64 + seg * 8) = o;
}

// ---------------- prep weights: B[r][128] = bf16([Wl[r]|Wr[r]]) ----------------
__global__ void prep_B(const float* __restrict__ Wl, const float* __restrict__ Wr,
                       u16* __restrict__ B, int nrows_src, int nrows_dst) {
    int i = blockIdx.x * 256 + threadIdx.x;
    if (i >= nrows_dst * 128) return;
    int r = i >> 7, k = i & 127;
    float v = 0.f;
    if (r < nrows_src) v = (k < 64) ? Wl[r * 64 + k] : Wr[r * 64 + k - 64];
    B[i] = f2bf(v);
}

// ---------------- pull aggregation on bf16 panels ----------------
__global__ __launch_bounds__(256) void pull_bf16(const u16* __restrict__ Asrc,
                                                 const int* __restrict__ row_ptr,
                                                 const int* __restrict__ nbr,
                                                 u16* __restrict__ Adst, int n) {
    int tid = blockIdx.x * 256 + threadIdx.x;
    int node = tid >> 3;
    int q = tid & 7;
    if (node >= n) return;
    int beg = row_ptr[node], end = row_ptr[node + 1];
    float a0 = 0.f, a1 = 0.f, a2 = 0.f, a3 = 0.f, a4 = 0.f, a5 = 0.f, a6 = 0.f, a7 = 0.f;
    for (int j = beg; j < end; ++j) {
        int s = nbr[j];
        uint4 v = *(const uint4*)(Asrc + (size_t)s * 128 + 64 + q * 8);
        a0 += bf_lo(v.x); a1 += bf_hi(v.x);
        a2 += bf_lo(v.y); a3 += bf_hi(v.y);
        a4 += bf_lo(v.z); a5 += bf_hi(v.z);
        a6 += bf_lo(v.w); a7 += bf_hi(v.w);
    }
    uint4 o;
    o.x = (u32)f2bf(a0) | ((u32)f2bf(a1) << 16);
    o.y = (u32)f2bf(a2) | ((u32)f2bf(a3) << 16);
    o.z = (u32)f2bf(a4) | ((u32)f2bf(a5) << 16);
    o.w = (u32)f2bf(a6) | ((u32)f2bf(a7) << 16);
    *(uint4*)(Adst + (size_t)node * 128 + q * 8) = o;
}

// ---------------- MFMA GEMM: [64 nodes] x [NT*16 cols], K=128 ----------------
template<int NT, bool RELU, bool OUT_BF16>
__global__ __launch_bounds__(256) void gemm_kernel(
    const u16* __restrict__ A, const u16* __restrict__ B,
    const float* __restrict__ bias,
    float* __restrict__ outf, u16* __restrict__ outb,
    int n_nodes, int n_cols)
{
    constexpr int KC = (NT == 16) ? 2 : 1;
    constexpr int KW = 128 / KC;
    constexpr int RG = KW / 8;
    constexpr int NR = NT * 16;
    __shared__ uint4 A_lds[64 * 16];
    __shared__ uint4 B_lds[2048];

    const int t = threadIdx.x;
    const int node0 = blockIdx.x * 64;

#pragma unroll
    for (int i = 0; i < 4; ++i) {
        int gl = t + 256 * i;
        int r = gl >> 4, g = gl & 15;
        uint4 v = make_uint4(0u, 0u, 0u, 0u);
        int node = node0 + r;
        if (node < n_nodes) v = *(const uint4*)(A + (size_t)node * 128 + g * 8);
        A_lds[r * 16 + (g ^ (r & 7))] = v;
    }

    const int w  = t >> 6;
    const int l  = t & 63;
    const int lm = l & 15;
    const int lg = l >> 4;
    const int arow = w * 16 + lm;
    const int asw  = arow & 7;

    f32x4 acc[NT];
#pragma unroll
    for (int n = 0; n < NT; ++n) acc[n] = f32x4{0.f, 0.f, 0.f, 0.f};

#pragma unroll
    for (int kc = 0; kc < KC; ++kc) {
        __syncthreads();
#pragma unroll
        for (int i = 0; i < (NR * RG) / 256; ++i) {
            int gl = t + 256 * i;
            int r = gl / RG, g = gl % RG;
            uint4 v = *(const uint4*)(B + (size_t)r * 128 + kc * KW + g * 8);
            B_lds[r * RG + (g ^ (r & 7))] = v;
        }
        __syncthreads();
#pragma unroll
        for (int ks = 0; ks < KW / 32; ++ks) {
            int ag = lg + (kc * (KW / 32) + ks) * 4;
            bf16x8 af = __builtin_bit_cast(bf16x8, A_lds[arow * 16 + (ag ^ asw)]);
#pragma unroll
            for (int n = 0; n < NT; ++n) {
                int brow = n * 16 + lm;
                int bg = lg + ks * 4;
                bf16x8 bf = __builtin_bit_cast(bf16x8, B_lds[brow * RG + (bg ^ (brow & 7))]);
                acc[n] = __builtin_amdgcn_mfma_f32_16x16x32_bf16(af, bf, acc[n], 0, 0, 0);
            }
        }
    }

    const int rbase = w * 16 + lg * 4;
#pragma unroll
    for (int n = 0; n < NT; ++n) {
        int c = n * 16 + lm;
        float bv = (c < n_cols) ? bias[c] : 0.f;
#pragma unroll
        for (int r = 0; r < 4; ++r) {
            int node = node0 + rbase + r;
            if (node < n_nodes && c < n_cols) {
                float v = acc[n][r] + bv;
                if (RELU) v = fmaxf(v, 0.f);
                if (OUT_BF16) outb[(size_t)node * 128 + 64 + c] = f2bf(v);
                else outf[(size_t)node * (size_t)n_cols + c] = v;
            }
        }
    }
}

extern "C" void kernel_launch(void* const* d_in, const int* in_sizes, int n_in,
                              void* d_out, int out_size, void* d_ws, size_t ws_size,
                              hipStream_t stream) {
    const float* x   = (const float*)d_in[0];
    const int*   ei  = (const int*)d_in[1];
    const float* W1l = (const float*)d_in[2];
    const float* b1  = (const float*)d_in[3];
    const float* W1r = (const float*)d_in[4];
    const float* W2l = (const float*)d_in[5];
    const float* b2  = (const float*)d_in[6];
    const float* W2r = (const float*)d_in[7];
    float* out = (float*)d_out;

    const int N = in_sizes[0] / DIM;     // 100000
    const int E = in_sizes[1] / 2;       // 1600000
    const int NPAD = ((N + 63) / 64) * 64;
    const int NB = (N + SCAN_CHUNK - 1) / SCAN_CHUNK;

    // workspace layout
    char* wp = (char*)d_ws;
    u16* A1 = (u16*)wp;                 wp += (size_t)NPAD * 128 * 2;
    u16* A2 = (u16*)wp;                 wp += (size_t)NPAD * 128 * 2;
    u16* B1 = (u16*)wp;                 wp += 64 * 128 * 2;
    u16* B2 = (u16*)wp;                 wp += 256 * 128 * 2;
    int* cnt     = (int*)wp;            wp += (size_t)N * 4;
    int* row_ptr = (int*)wp;            wp += (size_t)(N + 1) * 4;
    int* cursor  = (int*)wp;            wp += (size_t)N * 4;
    int* bsum    = (int*)wp;            wp += 1024 * 4;
    int* nbr     = (int*)wp;

    // partition geometry: 8 dst-ranges x 192 chunks
    const int npp = (N + NXCD - 1) / NXCD;            // nodes per partition
    const int NCHUNK = 192;
    const int chunk_size = (E + NCHUNK - 1) / NCHUNK;

    // ---- CSR build ----
    zero_i32<<<512, 256, 0, stream>>>(cnt, N);
    hist_part<<<NCHUNK * NXCD, 256, 0, stream>>>(ei + E, E, cnt, npp, chunk_size);
    scan_block_sums<<<NB, 256, 0, stream>>>(cnt, N, bsum);
    scan_bsum<<<1, 1024, 0, stream>>>(bsum, NB);
    scan_final<<<NB, 256, 0, stream>>>(cnt, N, bsum, row_ptr, cursor, E);
    fill_part<<<NCHUNK * NXCD, 256, 0, stream>>>(ei, E, cursor, nbr, npp, chunk_size);

    // ---- conversions / weight prep ----
    convert_x<<<(N * 8 + 255) / 256, 256, 0, stream>>>(x, A1, N * 8);
    prep_B<<<(64 * 128 + 255) / 256, 256, 0, stream>>>(W1l, W1r, B1, 64, 64);
    prep_B<<<(256 * 128 + 255) / 256, 256, 0, stream>>>(W2l, W2r, B2, NCLS, 256);

    const int gemm_blocks = NPAD / 64;

    // ---- layer 1 ----
    pull_bf16<<<(N * 8 + 255) / 256, 256, 0, stream>>>(A1, row_ptr, nbr, A1, N);
    gemm_kernel<4, true, true><<<gemm_blocks, 256, 0, stream>>>(A1, B1, b1, nullptr, A2, N, 64);

    // ---- layer 2 ----
    pull_bf16<<<(N * 8 + 255) / 256, 256, 0, stream>>>(A2, row_ptr, nbr, A2, N);
    gemm_kernel<16, false, false><<<gemm_blocks, 256, 0, stream>>>(A2, B2, b2, out, nullptr, N, NCLS);
}